// Round 2
// baseline (4867.579 us; speedup 1.0000x reference)
//
#include <hip/hip_runtime.h>

#define N_NODES 20000
#define N_EDGES 320000

__device__ __forceinline__ float4 ld4(const float* p) { return *(const float4*)p; }

// ---------------------------------------------------------------------------
// Generic small GEMM: C[M,N] = act(A[M,K] @ W[K,N] + bias)
// BM=64 BN=64 BK=32, 256 threads, 4x4 per thread.
// ---------------------------------------------------------------------------
template<bool SILU>
__global__ __launch_bounds__(256) void gemm64(
    const float* __restrict__ A, const float* __restrict__ W,
    const float* __restrict__ bias, float* __restrict__ C,
    int M, int K, int N)
{
  __shared__ __align__(16) float As[32][68];  // transposed A tile: As[k][m]
  __shared__ __align__(16) float Ws[32][68];
  const int m0 = blockIdx.y * 64, n0 = blockIdx.x * 64;
  const int t = threadIdx.x;
  const int tx = t & 15, ty = t >> 4;
  float acc[4][4] = {{0.f,0.f,0.f,0.f},{0.f,0.f,0.f,0.f},{0.f,0.f,0.f,0.f},{0.f,0.f,0.f,0.f}};

  for (int k0 = 0; k0 < K; k0 += 32) {
    {
      const int r = t >> 3, c4 = (t & 7) * 4;
      #pragma unroll
      for (int rr = 0; rr < 64; rr += 32) {
        const int gm = m0 + r + rr;
        float4 v = make_float4(0.f, 0.f, 0.f, 0.f);
        if (gm < M) v = ld4(A + (size_t)gm * K + k0 + c4);
        As[c4 + 0][r + rr] = v.x; As[c4 + 1][r + rr] = v.y;
        As[c4 + 2][r + rr] = v.z; As[c4 + 3][r + rr] = v.w;
      }
      const int wr = t >> 4, wc4 = (t & 15) * 4;
      #pragma unroll
      for (int rr = 0; rr < 32; rr += 16) {
        float4 v = ld4(W + (size_t)(k0 + wr + rr) * N + n0 + wc4);
        *(float4*)&Ws[wr + rr][wc4] = v;
      }
    }
    __syncthreads();
    #pragma unroll
    for (int kk = 0; kk < 32; ++kk) {
      float4 av = *(const float4*)&As[kk][ty * 4];
      float4 bv = *(const float4*)&Ws[kk][tx * 4];
      const float a[4] = {av.x, av.y, av.z, av.w};
      const float b[4] = {bv.x, bv.y, bv.z, bv.w};
      #pragma unroll
      for (int i = 0; i < 4; ++i)
        #pragma unroll
        for (int j = 0; j < 4; ++j)
          acc[i][j] += a[i] * b[j];
    }
    __syncthreads();
  }

  const float4 bv = ld4(bias + n0 + tx * 4);
  const float bb[4] = {bv.x, bv.y, bv.z, bv.w};
  #pragma unroll
  for (int i = 0; i < 4; ++i) {
    const int gm = m0 + ty * 4 + i;
    if (gm < M) {
      float o[4];
      #pragma unroll
      for (int j = 0; j < 4; ++j) {
        float v = acc[i][j] + bb[j];
        if (SILU) v = v / (1.f + __expf(-v));
        o[j] = v;
      }
      float4 ov = make_float4(o[0], o[1], o[2], o[3]);
      *(float4*)&C[(size_t)gm * N + n0 + tx * 4] = ov;
    }
  }
}

// ---------------------------------------------------------------------------
// Shared gather + LayerNorm for the edge kernels.
// feat[e][0..63]   = raw edge_attr (kept raw; LN applied on the fly in GEMM)
// feat[e][64..575] = LayerNormed x[src] / p[dst]
// ---------------------------------------------------------------------------
__device__ __forceinline__ void gather_ln(
    float (*feat)[580], int* src_s, int* dst_s, float* mu_s, float* rstd_s,
    const float* __restrict__ x, const float* __restrict__ p,
    const float* __restrict__ ea, const int* __restrict__ eidx,
    const float* __restrict__ lnw, const float* __restrict__ lnb,
    int eb, int t)
{
  if (t < 32) src_s[t] = eidx[eb + t];
  else if (t < 64) dst_s[t - 32] = eidx[N_EDGES + eb + (t - 32)];
  __syncthreads();

  // gather: 32 edges x 144 float4 = 288 chunks of 16 float4 (64B/lane-quad)
  {
    const int cid0 = t >> 4, l16 = t & 15;
    #pragma unroll
    for (int it = 0; it < 18; ++it) {
      const int cid = it * 16 + cid0;  // 0..287
      const int e = cid & 31;
      const int s = cid >> 5;          // 0..8
      const float* sp;
      if (s == 0)      sp = ea + (size_t)(eb + e) * 64 + l16 * 4;
      else if (s <= 4) sp = x + (size_t)src_s[e] * 256 + ((s - 1) * 16 + l16) * 4;
      else             sp = p + (size_t)dst_s[e] * 256 + ((s - 5) * 16 + l16) * 4;
      float4 v = ld4(sp);
      *((float4*)&feat[e][0] + (s * 16 + l16)) = v;
    }
  }
  __syncthreads();

  // LN stats over all 576, in-place normalize cols 64..575
  {
    const int e = t >> 3, g = t & 7;
    float sum = 0.f, sq = 0.f;
    #pragma unroll
    for (int i = 0; i < 18; ++i) {
      float4 v = *((const float4*)&feat[e][0] + (g + 8 * i));
      sum += (v.x + v.y) + (v.z + v.w);
      sq += v.x * v.x + v.y * v.y + v.z * v.z + v.w * v.w;
    }
    sum += __shfl_xor(sum, 1); sq += __shfl_xor(sq, 1);
    sum += __shfl_xor(sum, 2); sq += __shfl_xor(sq, 2);
    sum += __shfl_xor(sum, 4); sq += __shfl_xor(sq, 4);
    const float mu = sum * (1.f / 576.f);
    const float var = sq * (1.f / 576.f) - mu * mu;
    const float rstd = rsqrtf(var + 1e-5f);
    if (g == 0) { mu_s[e] = mu; rstd_s[e] = rstd; }
    #pragma unroll
    for (int i = 0; i < 16; ++i) {
      const int idx = 16 + g + 8 * i;  // float4 index 16..143 (cols 64..575)
      float4 v = *((const float4*)&feat[e][0] + idx);
      const float4 wv = ld4(lnw + idx * 4);
      const float4 bv = ld4(lnb + idx * 4);
      v.x = (v.x - mu) * rstd * wv.x + bv.x;
      v.y = (v.y - mu) * rstd * wv.y + bv.y;
      v.z = (v.z - mu) * rstd * wv.z + bv.z;
      v.w = (v.w - mu) * rstd * wv.w + bv.w;
      *((float4*)&feat[e][0] + idx) = v;
    }
  }
  __syncthreads();
}

// ---------------------------------------------------------------------------
// Per-thread 4-edge x 8-col GEMM over the 576-wide LN'd features.
// Thread (er,jg): edges {er, er+8, er+16, er+24}, cols j0..j0+7.
// W streamed from global (L1/L2-resident per block).
// ---------------------------------------------------------------------------
__device__ __forceinline__ void edge_gemm(
    const float (*feat)[580], const float* mu_s, const float* rstd_s,
    const float* __restrict__ Wm, const float* __restrict__ bm,
    const float* __restrict__ lnw, const float* __restrict__ lnb,
    int er, int jg, float acc[4][8])
{
  const int j0 = jg * 8;
  const float4 bv0 = ld4(bm + j0), bv1 = ld4(bm + j0 + 4);
  #pragma unroll
  for (int i = 0; i < 4; ++i) {
    acc[i][0] = bv0.x; acc[i][1] = bv0.y; acc[i][2] = bv0.z; acc[i][3] = bv0.w;
    acc[i][4] = bv1.x; acc[i][5] = bv1.y; acc[i][6] = bv1.z; acc[i][7] = bv1.w;
  }
  float mu_[4], rs_[4];
  #pragma unroll
  for (int i = 0; i < 4; ++i) { mu_[i] = mu_s[er + 8 * i]; rs_[i] = rstd_s[er + 8 * i]; }

  // quads 0..15: raw edge_attr rows, LN applied on the fly
  #pragma unroll 2
  for (int kq = 0; kq < 16; ++kq) {
    const int kk = kq * 4;
    float a[4][4];
    #pragma unroll
    for (int i = 0; i < 4; ++i)
      *(float4*)&a[i][0] = *((const float4*)&feat[er + 8 * i][0] + kq);
    const float4 wv = ld4(lnw + kk);
    const float4 lbv = ld4(lnb + kk);
    #pragma unroll
    for (int i = 0; i < 4; ++i) {
      a[i][0] = (a[i][0] - mu_[i]) * rs_[i] * wv.x + lbv.x;
      a[i][1] = (a[i][1] - mu_[i]) * rs_[i] * wv.y + lbv.y;
      a[i][2] = (a[i][2] - mu_[i]) * rs_[i] * wv.z + lbv.z;
      a[i][3] = (a[i][3] - mu_[i]) * rs_[i] * wv.w + lbv.w;
    }
    float w[4][8];
    #pragma unroll
    for (int r = 0; r < 4; ++r) {
      *(float4*)&w[r][0] = ld4(Wm + (size_t)(kk + r) * 256 + j0);
      *(float4*)&w[r][4] = ld4(Wm + (size_t)(kk + r) * 256 + j0 + 4);
    }
    #pragma unroll
    for (int r = 0; r < 4; ++r)
      #pragma unroll
      for (int i = 0; i < 4; ++i)
        #pragma unroll
        for (int c = 0; c < 8; ++c)
          acc[i][c] += a[i][r] * w[r][c];
  }

  // quads 16..143: already-normalized rows
  #pragma unroll 2
  for (int kq = 16; kq < 144; ++kq) {
    const int kk = kq * 4;
    float a[4][4];
    #pragma unroll
    for (int i = 0; i < 4; ++i)
      *(float4*)&a[i][0] = *((const float4*)&feat[er + 8 * i][0] + kq);
    float w[4][8];
    #pragma unroll
    for (int r = 0; r < 4; ++r) {
      *(float4*)&w[r][0] = ld4(Wm + (size_t)(kk + r) * 256 + j0);
      *(float4*)&w[r][4] = ld4(Wm + (size_t)(kk + r) * 256 + j0 + 4);
    }
    #pragma unroll
    for (int r = 0; r < 4; ++r)
      #pragma unroll
      for (int i = 0; i < 4; ++i)
        #pragma unroll
        for (int c = 0; c < 8; ++c)
          acc[i][c] += a[i][r] * w[r][c];
  }
}

// ---------------------------------------------------------------------------
// K pass: k = LN(feat) @ Wk + bk; scores = dot(q[src], k)/sqrt(32);
// ex = exp(score) (max-subtraction skipped: mathematically identical, scores O(1));
// ssum[src][h] += ex (atomic).
// ---------------------------------------------------------------------------
__global__ __launch_bounds__(256) void edge_k_kernel(
    const float* __restrict__ x, const float* __restrict__ p,
    const float* __restrict__ ea, const int* __restrict__ eidx,
    const float* __restrict__ lnw, const float* __restrict__ lnb,
    const float* __restrict__ Wk, const float* __restrict__ bk,
    const float* __restrict__ q, float* __restrict__ exb, float* __restrict__ ssum)
{
  __shared__ __align__(16) float feat[32][580];
  __shared__ float mu_s[32], rstd_s[32];
  __shared__ int src_s[32], dst_s[32];
  const int t = threadIdx.x;
  const int eb = blockIdx.x * 32;
  gather_ln(feat, src_s, dst_s, mu_s, rstd_s, x, p, ea, eidx, lnw, lnb, eb, t);

  const int er = t & 7, jg = t >> 3;
  const int j0 = jg * 8;
  float acc[4][8];
  edge_gemm(feat, mu_s, rstd_s, Wk, bk, lnw, lnb, er, jg, acc);

  const int h = jg >> 2;  // head = j0/32
  #pragma unroll
  for (int i = 0; i < 4; ++i) {
    const int e = er + 8 * i;
    const int sn = src_s[e];
    const float* qr = q + (size_t)sn * 256 + j0;
    const float4 q0 = ld4(qr), q1 = ld4(qr + 4);
    float d = acc[i][0] * q0.x + acc[i][1] * q0.y + acc[i][2] * q0.z + acc[i][3] * q0.w
            + acc[i][4] * q1.x + acc[i][5] * q1.y + acc[i][6] * q1.z + acc[i][7] * q1.w;
    d += __shfl_xor(d, 8);   // combine jg pairs within head
    d += __shfl_xor(d, 16);
    if ((jg & 3) == 0) {
      const float ev = __expf(d * 0.17677669529663687f);  // 1/sqrt(32)
      exb[(size_t)(eb + e) * 8 + h] = ev;
      atomicAdd(&ssum[(size_t)sn * 8 + h], ev);
    }
  }
}

// ---------------------------------------------------------------------------
// V pass: v = LN(feat) @ Wv + bv; eg = edge_attr @ We;
// attn[src] += (ex/ssum[src]) * v * eg (atomic scatter).
// ---------------------------------------------------------------------------
__global__ __launch_bounds__(256) void edge_v_kernel(
    const float* __restrict__ x, const float* __restrict__ p,
    const float* __restrict__ ea, const int* __restrict__ eidx,
    const float* __restrict__ lnw, const float* __restrict__ lnb,
    const float* __restrict__ Wv, const float* __restrict__ bv,
    const float* __restrict__ We, const float* __restrict__ exb,
    const float* __restrict__ ssum, float* __restrict__ attn)
{
  __shared__ __align__(16) float feat[32][580];
  __shared__ float mu_s[32], rstd_s[32];
  __shared__ int src_s[32], dst_s[32];
  const int t = threadIdx.x;
  const int eb = blockIdx.x * 32;
  gather_ln(feat, src_s, dst_s, mu_s, rstd_s, x, p, ea, eidx, lnw, lnb, eb, t);

  const int er = t & 7, jg = t >> 3;
  const int j0 = jg * 8;
  float vacc[4][8];
  edge_gemm(feat, mu_s, rstd_s, Wv, bv, lnw, lnb, er, jg, vacc);

  // eg = raw edge_attr @ We (rows 0..63 of feat are still raw)
  float ga[4][8];
  #pragma unroll
  for (int i = 0; i < 4; ++i)
    #pragma unroll
    for (int c = 0; c < 8; ++c) ga[i][c] = 0.f;
  #pragma unroll 2
  for (int kq = 0; kq < 16; ++kq) {
    const int kk = kq * 4;
    float a[4][4];
    #pragma unroll
    for (int i = 0; i < 4; ++i)
      *(float4*)&a[i][0] = *((const float4*)&feat[er + 8 * i][0] + kq);
    float w[4][8];
    #pragma unroll
    for (int r = 0; r < 4; ++r) {
      *(float4*)&w[r][0] = ld4(We + (size_t)(kk + r) * 256 + j0);
      *(float4*)&w[r][4] = ld4(We + (size_t)(kk + r) * 256 + j0 + 4);
    }
    #pragma unroll
    for (int r = 0; r < 4; ++r)
      #pragma unroll
      for (int i = 0; i < 4; ++i)
        #pragma unroll
        for (int c = 0; c < 8; ++c)
          ga[i][c] += a[i][r] * w[r][c];
  }

  const int h = jg >> 2;
  #pragma unroll
  for (int i = 0; i < 4; ++i) {
    const int e = er + 8 * i;
    const int sn = src_s[e];
    const float alpha = exb[(size_t)(eb + e) * 8 + h] / ssum[(size_t)sn * 8 + h];
    float* orow = attn + (size_t)sn * 256 + j0;
    #pragma unroll
    for (int c = 0; c < 8; ++c)
      atomicAdd(orow + c, alpha * vacc[i][c] * ga[i][c]);
  }
}

// ---------------------------------------------------------------------------
extern "C" void kernel_launch(void* const* d_in, const int* in_sizes, int n_in,
                              void* d_out, int out_size, void* d_ws, size_t ws_size,
                              hipStream_t stream)
{
  const float* x   = (const float*)d_in[0];
  const float* p   = (const float*)d_in[1];
  const float* ea  = (const float*)d_in[2];
  const int*   ei  = (const int*)d_in[3];
  const float* lnw = (const float*)d_in[4];
  const float* lnb = (const float*)d_in[5];
  const float* Wq  = (const float*)d_in[6];
  const float* bq  = (const float*)d_in[7];
  const float* Wk  = (const float*)d_in[8];
  const float* bk  = (const float*)d_in[9];
  const float* Wv  = (const float*)d_in[10];
  const float* bv  = (const float*)d_in[11];
  const float* We  = (const float*)d_in[12];
  const float* W1  = (const float*)d_in[13];
  const float* b1  = (const float*)d_in[14];
  const float* W2  = (const float*)d_in[15];
  const float* b2  = (const float*)d_in[16];
  float* out = (float*)d_out;

  // workspace layout (floats): q | ex | ssum | attn | h   (total 92.8 MB)
  float* q    = (float*)d_ws;
  float* exb  = q + (size_t)N_NODES * 256;
  float* ssum = exb + (size_t)N_EDGES * 8;
  float* attn = ssum + (size_t)N_NODES * 8;
  float* hbuf = attn + (size_t)N_NODES * 256;

  hipMemsetAsync(ssum, 0, (size_t)N_NODES * 8 * sizeof(float), stream);
  hipMemsetAsync(attn, 0, (size_t)N_NODES * 256 * sizeof(float), stream);

  dim3 blk(256);
  // q = x @ Wq + bq
  gemm64<false><<<dim3(4, 313), blk, 0, stream>>>(x, Wq, bq, q, N_NODES, 256, 256);
  // k + scores + softmax denominators
  edge_k_kernel<<<dim3(N_EDGES / 32), blk, 0, stream>>>(x, p, ea, ei, lnw, lnb, Wk, bk, q, exb, ssum);
  // v + eg + weighted scatter
  edge_v_kernel<<<dim3(N_EDGES / 32), blk, 0, stream>>>(x, p, ea, ei, lnw, lnb, Wv, bv, We, exb, ssum, attn);
  // MLP
  gemm64<true><<<dim3(8, 313), blk, 0, stream>>>(attn, W1, b1, hbuf, N_NODES, 256, 512);
  gemm64<false><<<dim3(4, 313), blk, 0, stream>>>(hbuf, W2, b2, out, N_NODES, 512, 256);
}

// Round 3
// 3837.343 us; speedup vs baseline: 1.2685x; 1.2685x over previous
//
#include <hip/hip_runtime.h>

#define N_NODES 20000
#define N_EDGES 320000

__device__ __forceinline__ float4 ld4(const float* p) { return *(const float4*)p; }

__device__ __forceinline__ unsigned short f2bf(float f) {
  unsigned int u = __float_as_uint(f);
  return (unsigned short)((u + 0x7FFFu + ((u >> 16) & 1u)) >> 16);  // RNE
}
__device__ __forceinline__ float bf2f(unsigned short b) {
  return __uint_as_float(((unsigned int)b) << 16);
}

// ---------------------------------------------------------------------------
// Generic small GEMM: C[M,N] = act(A[M,K] @ W[K,N] + bias)
// BM=64 BN=64 BK=32, 256 threads, 4x4 per thread.
// ---------------------------------------------------------------------------
template<bool SILU>
__global__ __launch_bounds__(256) void gemm64(
    const float* __restrict__ A, const float* __restrict__ W,
    const float* __restrict__ bias, float* __restrict__ C,
    int M, int K, int N)
{
  __shared__ __align__(16) float As[32][68];  // transposed A tile: As[k][m]
  __shared__ __align__(16) float Ws[32][68];
  const int m0 = blockIdx.y * 64, n0 = blockIdx.x * 64;
  const int t = threadIdx.x;
  const int tx = t & 15, ty = t >> 4;
  float acc[4][4] = {{0.f,0.f,0.f,0.f},{0.f,0.f,0.f,0.f},{0.f,0.f,0.f,0.f},{0.f,0.f,0.f,0.f}};

  for (int k0 = 0; k0 < K; k0 += 32) {
    {
      const int r = t >> 3, c4 = (t & 7) * 4;
      #pragma unroll
      for (int rr = 0; rr < 64; rr += 32) {
        const int gm = m0 + r + rr;
        float4 v = make_float4(0.f, 0.f, 0.f, 0.f);
        if (gm < M) v = ld4(A + (size_t)gm * K + k0 + c4);
        As[c4 + 0][r + rr] = v.x; As[c4 + 1][r + rr] = v.y;
        As[c4 + 2][r + rr] = v.z; As[c4 + 3][r + rr] = v.w;
      }
      const int wr = t >> 4, wc4 = (t & 15) * 4;
      #pragma unroll
      for (int rr = 0; rr < 32; rr += 16) {
        float4 v = ld4(W + (size_t)(k0 + wr + rr) * N + n0 + wc4);
        *(float4*)&Ws[wr + rr][wc4] = v;
      }
    }
    __syncthreads();
    #pragma unroll
    for (int kk = 0; kk < 32; ++kk) {
      float4 av = *(const float4*)&As[kk][ty * 4];
      float4 bv = *(const float4*)&Ws[kk][tx * 4];
      const float a[4] = {av.x, av.y, av.z, av.w};
      const float b[4] = {bv.x, bv.y, bv.z, bv.w};
      #pragma unroll
      for (int i = 0; i < 4; ++i)
        #pragma unroll
        for (int j = 0; j < 4; ++j)
          acc[i][j] += a[i] * b[j];
    }
    __syncthreads();
  }

  const float4 bv = ld4(bias + n0 + tx * 4);
  const float bb[4] = {bv.x, bv.y, bv.z, bv.w};
  #pragma unroll
  for (int i = 0; i < 4; ++i) {
    const int gm = m0 + ty * 4 + i;
    if (gm < M) {
      float o[4];
      #pragma unroll
      for (int j = 0; j < 4; ++j) {
        float v = acc[i][j] + bb[j];
        if (SILU) v = v / (1.f + __expf(-v));
        o[j] = v;
      }
      float4 ov = make_float4(o[0], o[1], o[2], o[3]);
      *(float4*)&C[(size_t)gm * N + n0 + tx * 4] = ov;
    }
  }
}

// ---------------------------------------------------------------------------
// Shared gather + LayerNorm for the edge kernel.
// feat[e][0..63]   = raw edge_attr (kept raw; LN applied on the fly in GEMM)
// feat[e][64..575] = LayerNormed x[src] / p[dst]
// ---------------------------------------------------------------------------
__device__ __forceinline__ void gather_ln(
    float (*feat)[580], int* src_s, int* dst_s, float* mu_s, float* rstd_s,
    const float* __restrict__ x, const float* __restrict__ p,
    const float* __restrict__ ea, const int* __restrict__ eidx,
    const float* __restrict__ lnw, const float* __restrict__ lnb,
    int eb, int t)
{
  if (t < 32) src_s[t] = eidx[eb + t];
  else if (t < 64) dst_s[t - 32] = eidx[N_EDGES + eb + (t - 32)];
  __syncthreads();

  // gather: 32 edges x 144 float4 = 288 chunks of 16 float4 (64B/lane-quad)
  {
    const int cid0 = t >> 4, l16 = t & 15;
    #pragma unroll
    for (int it = 0; it < 18; ++it) {
      const int cid = it * 16 + cid0;  // 0..287
      const int e = cid & 31;
      const int s = cid >> 5;          // 0..8
      const float* sp;
      if (s == 0)      sp = ea + (size_t)(eb + e) * 64 + l16 * 4;
      else if (s <= 4) sp = x + (size_t)src_s[e] * 256 + ((s - 1) * 16 + l16) * 4;
      else             sp = p + (size_t)dst_s[e] * 256 + ((s - 5) * 16 + l16) * 4;
      float4 v = ld4(sp);
      *((float4*)&feat[e][0] + (s * 16 + l16)) = v;
    }
  }
  __syncthreads();

  // LN stats over all 576, in-place normalize cols 64..575
  {
    const int e = t >> 3, g = t & 7;
    float sum = 0.f, sq = 0.f;
    #pragma unroll
    for (int i = 0; i < 18; ++i) {
      float4 v = *((const float4*)&feat[e][0] + (g + 8 * i));
      sum += (v.x + v.y) + (v.z + v.w);
      sq += v.x * v.x + v.y * v.y + v.z * v.z + v.w * v.w;
    }
    sum += __shfl_xor(sum, 1); sq += __shfl_xor(sq, 1);
    sum += __shfl_xor(sum, 2); sq += __shfl_xor(sq, 2);
    sum += __shfl_xor(sum, 4); sq += __shfl_xor(sq, 4);
    const float mu = sum * (1.f / 576.f);
    const float var = sq * (1.f / 576.f) - mu * mu;
    const float rstd = rsqrtf(var + 1e-5f);
    if (g == 0) { mu_s[e] = mu; rstd_s[e] = rstd; }
    #pragma unroll
    for (int i = 0; i < 16; ++i) {
      const int idx = 16 + g + 8 * i;  // float4 index 16..143 (cols 64..575)
      float4 v = *((const float4*)&feat[e][0] + idx);
      const float4 wv = ld4(lnw + idx * 4);
      const float4 bv = ld4(lnb + idx * 4);
      v.x = (v.x - mu) * rstd * wv.x + bv.x;
      v.y = (v.y - mu) * rstd * wv.y + bv.y;
      v.z = (v.z - mu) * rstd * wv.z + bv.z;
      v.w = (v.w - mu) * rstd * wv.w + bv.w;
      *((float4*)&feat[e][0] + idx) = v;
    }
  }
  __syncthreads();
}

// ---------------------------------------------------------------------------
// Per-thread 4-edge x 8-col GEMM over the 576-wide LN'd features.
// Thread (er,jg): edges {er, er+8, er+16, er+24}, cols j0..j0+7.
// ---------------------------------------------------------------------------
__device__ __forceinline__ void edge_gemm(
    const float (*feat)[580], const float* mu_s, const float* rstd_s,
    const float* __restrict__ Wm, const float* __restrict__ bm,
    const float* __restrict__ lnw, const float* __restrict__ lnb,
    int er, int jg, float acc[4][8])
{
  const int j0 = jg * 8;
  const float4 bv0 = ld4(bm + j0), bv1 = ld4(bm + j0 + 4);
  #pragma unroll
  for (int i = 0; i < 4; ++i) {
    acc[i][0] = bv0.x; acc[i][1] = bv0.y; acc[i][2] = bv0.z; acc[i][3] = bv0.w;
    acc[i][4] = bv1.x; acc[i][5] = bv1.y; acc[i][6] = bv1.z; acc[i][7] = bv1.w;
  }
  float mu_[4], rs_[4];
  #pragma unroll
  for (int i = 0; i < 4; ++i) { mu_[i] = mu_s[er + 8 * i]; rs_[i] = rstd_s[er + 8 * i]; }

  // quads 0..15: raw edge_attr rows, LN applied on the fly
  #pragma unroll 2
  for (int kq = 0; kq < 16; ++kq) {
    const int kk = kq * 4;
    float a[4][4];
    #pragma unroll
    for (int i = 0; i < 4; ++i)
      *(float4*)&a[i][0] = *((const float4*)&feat[er + 8 * i][0] + kq);
    const float4 wv = ld4(lnw + kk);
    const float4 lbv = ld4(lnb + kk);
    #pragma unroll
    for (int i = 0; i < 4; ++i) {
      a[i][0] = (a[i][0] - mu_[i]) * rs_[i] * wv.x + lbv.x;
      a[i][1] = (a[i][1] - mu_[i]) * rs_[i] * wv.y + lbv.y;
      a[i][2] = (a[i][2] - mu_[i]) * rs_[i] * wv.z + lbv.z;
      a[i][3] = (a[i][3] - mu_[i]) * rs_[i] * wv.w + lbv.w;
    }
    float w[4][8];
    #pragma unroll
    for (int r = 0; r < 4; ++r) {
      *(float4*)&w[r][0] = ld4(Wm + (size_t)(kk + r) * 256 + j0);
      *(float4*)&w[r][4] = ld4(Wm + (size_t)(kk + r) * 256 + j0 + 4);
    }
    #pragma unroll
    for (int r = 0; r < 4; ++r)
      #pragma unroll
      for (int i = 0; i < 4; ++i)
        #pragma unroll
        for (int c = 0; c < 8; ++c)
          acc[i][c] += a[i][r] * w[r][c];
  }

  // quads 16..143: already-normalized rows
  #pragma unroll 2
  for (int kq = 16; kq < 144; ++kq) {
    const int kk = kq * 4;
    float a[4][4];
    #pragma unroll
    for (int i = 0; i < 4; ++i)
      *(float4*)&a[i][0] = *((const float4*)&feat[er + 8 * i][0] + kq);
    float w[4][8];
    #pragma unroll
    for (int r = 0; r < 4; ++r) {
      *(float4*)&w[r][0] = ld4(Wm + (size_t)(kk + r) * 256 + j0);
      *(float4*)&w[r][4] = ld4(Wm + (size_t)(kk + r) * 256 + j0 + 4);
    }
    #pragma unroll
    for (int r = 0; r < 4; ++r)
      #pragma unroll
      for (int i = 0; i < 4; ++i)
        #pragma unroll
        for (int c = 0; c < 8; ++c)
          acc[i][c] += a[i][r] * w[r][c];
  }
}

// ---------------------------------------------------------------------------
// Fused edge pass:
//   k = LN(feat)@Wk+bk; score = dot(q[src],k)/sqrt(32); ex = exp(score)
//   ssum[src][h] += ex (atomic; only softmax denominators are atomic now)
//   v = LN(feat)@Wv+bv; eg = edge_attr@We
//   m[e] = ex * v * eg  (bf16, coalesced write — normalization deferred)
// ---------------------------------------------------------------------------
__global__ __launch_bounds__(256) void edge_fused_kernel(
    const float* __restrict__ x, const float* __restrict__ p,
    const float* __restrict__ ea, const int* __restrict__ eidx,
    const float* __restrict__ lnw, const float* __restrict__ lnb,
    const float* __restrict__ Wk, const float* __restrict__ bk,
    const float* __restrict__ Wv, const float* __restrict__ bv,
    const float* __restrict__ We, const float* __restrict__ q,
    float* __restrict__ ssum, unsigned short* __restrict__ mbuf)
{
  __shared__ __align__(16) float feat[32][580];
  __shared__ float mu_s[32], rstd_s[32];
  __shared__ int src_s[32], dst_s[32];
  const int t = threadIdx.x;
  const int eb = blockIdx.x * 32;
  gather_ln(feat, src_s, dst_s, mu_s, rstd_s, x, p, ea, eidx, lnw, lnb, eb, t);

  const int er = t & 7, jg = t >> 3;
  const int j0 = jg * 8;
  const int h = jg >> 2;

  // ---- K phase ----
  float acc[4][8];
  edge_gemm(feat, mu_s, rstd_s, Wk, bk, lnw, lnb, er, jg, acc);

  float exv[4];
  #pragma unroll
  for (int i = 0; i < 4; ++i) {
    const int e = er + 8 * i;
    const int sn = src_s[e];
    const float* qr = q + (size_t)sn * 256 + j0;
    const float4 q0 = ld4(qr), q1 = ld4(qr + 4);
    float d = acc[i][0] * q0.x + acc[i][1] * q0.y + acc[i][2] * q0.z + acc[i][3] * q0.w
            + acc[i][4] * q1.x + acc[i][5] * q1.y + acc[i][6] * q1.z + acc[i][7] * q1.w;
    d += __shfl_xor(d, 8);   // after both xors every lane holds its head's full dot
    d += __shfl_xor(d, 16);
    exv[i] = __expf(d * 0.17677669529663687f);  // 1/sqrt(32); max-sub skipped (exact)
    if ((jg & 3) == 0)
      atomicAdd(&ssum[(size_t)sn * 8 + h], exv[i]);
  }

  // ---- V phase (reuse acc) ----
  edge_gemm(feat, mu_s, rstd_s, Wv, bv, lnw, lnb, er, jg, acc);

  // eg = raw edge_attr @ We (rows 0..63 of feat still raw)
  float ga[4][8];
  #pragma unroll
  for (int i = 0; i < 4; ++i)
    #pragma unroll
    for (int c = 0; c < 8; ++c) ga[i][c] = 0.f;
  #pragma unroll 2
  for (int kq = 0; kq < 16; ++kq) {
    const int kk = kq * 4;
    float a[4][4];
    #pragma unroll
    for (int i = 0; i < 4; ++i)
      *(float4*)&a[i][0] = *((const float4*)&feat[er + 8 * i][0] + kq);
    float w[4][8];
    #pragma unroll
    for (int r = 0; r < 4; ++r) {
      *(float4*)&w[r][0] = ld4(We + (size_t)(kk + r) * 256 + j0);
      *(float4*)&w[r][4] = ld4(We + (size_t)(kk + r) * 256 + j0 + 4);
    }
    #pragma unroll
    for (int r = 0; r < 4; ++r)
      #pragma unroll
      for (int i = 0; i < 4; ++i)
        #pragma unroll
        for (int c = 0; c < 8; ++c)
          ga[i][c] += a[i][r] * w[r][c];
  }

  // ---- write unnormalized messages (bf16, 16B per edge-slice) ----
  #pragma unroll
  for (int i = 0; i < 4; ++i) {
    const int e = eb + er + 8 * i;
    unsigned int pk[4];
    #pragma unroll
    for (int c2 = 0; c2 < 4; ++c2) {
      const float f0 = exv[i] * acc[i][2 * c2]     * ga[i][2 * c2];
      const float f1 = exv[i] * acc[i][2 * c2 + 1] * ga[i][2 * c2 + 1];
      pk[c2] = (unsigned int)f2bf(f0) | ((unsigned int)f2bf(f1) << 16);
    }
    uint4 v = make_uint4(pk[0], pk[1], pk[2], pk[3]);
    *(uint4*)&mbuf[(size_t)e * 256 + j0] = v;
  }
}

// ---------------------------------------------------------------------------
// CSR build: histogram -> single-block scan -> scatter
// ---------------------------------------------------------------------------
__global__ void hist_kernel(const int* __restrict__ eidx, int* __restrict__ deg)
{
  const int e = blockIdx.x * 256 + threadIdx.x;
  if (e < N_EDGES) atomicAdd(&deg[eidx[e]], 1);
}

__global__ __launch_bounds__(1024) void scan_kernel(
    const int* __restrict__ deg, int* __restrict__ off, int* __restrict__ cursor)
{
  __shared__ int part[1024];
  const int t = threadIdx.x;
  const int base = t * 20;
  int s = 0;
  #pragma unroll 4
  for (int j = 0; j < 20; ++j) {
    const int n = base + j;
    if (n < N_NODES) s += deg[n];
  }
  part[t] = s;
  __syncthreads();
  for (int st = 1; st < 1024; st <<= 1) {
    int v = (t >= st) ? part[t - st] : 0;
    __syncthreads();
    part[t] += v;
    __syncthreads();
  }
  int run = (t == 0) ? 0 : part[t - 1];
  for (int j = 0; j < 20; ++j) {
    const int n = base + j;
    if (n < N_NODES) {
      off[n] = run;
      cursor[n] = run;
      run += deg[n];
    }
  }
  if (t == 1023) off[N_NODES] = part[1023];
}

__global__ void scatter_kernel(const int* __restrict__ eidx,
                               int* __restrict__ cursor, int* __restrict__ order)
{
  const int e = blockIdx.x * 256 + threadIdx.x;
  if (e < N_EDGES) {
    const int s = eidx[e];
    const int pos = atomicAdd(&cursor[s], 1);
    order[pos] = e;
  }
}

// ---------------------------------------------------------------------------
// Node gather: attn[n][c] = (sum_{e in node n} m[e][c]) / ssum[n][c/32]
// One wave per node, 4 bf16 cols per lane.
// ---------------------------------------------------------------------------
__global__ __launch_bounds__(64) void gather_kernel(
    const unsigned short* __restrict__ mbuf, const int* __restrict__ off,
    const int* __restrict__ order, const float* __restrict__ ssum,
    float* __restrict__ attn)
{
  const int n = blockIdx.x;
  const int t = threadIdx.x;
  const int c0 = t * 4;
  const int o0 = off[n], o1 = off[n + 1];
  float a0 = 0.f, a1 = 0.f, a2 = 0.f, a3 = 0.f;
  for (int j = o0; j < o1; ++j) {
    const int e = order[j];
    const ushort4 raw = *(const ushort4*)&mbuf[(size_t)e * 256 + c0];
    a0 += bf2f(raw.x); a1 += bf2f(raw.y); a2 += bf2f(raw.z); a3 += bf2f(raw.w);
  }
  const int h = c0 >> 5;
  float inv = 0.f;
  if (o1 > o0) inv = 1.f / ssum[(size_t)n * 8 + h];
  float4 o = make_float4(a0 * inv, a1 * inv, a2 * inv, a3 * inv);
  *(float4*)&attn[(size_t)n * 256 + c0] = o;
}

// ---------------------------------------------------------------------------
extern "C" void kernel_launch(void* const* d_in, const int* in_sizes, int n_in,
                              void* d_out, int out_size, void* d_ws, size_t ws_size,
                              hipStream_t stream)
{
  const float* x   = (const float*)d_in[0];
  const float* p   = (const float*)d_in[1];
  const float* ea  = (const float*)d_in[2];
  const int*   ei  = (const int*)d_in[3];
  const float* lnw = (const float*)d_in[4];
  const float* lnb = (const float*)d_in[5];
  const float* Wq  = (const float*)d_in[6];
  const float* bq  = (const float*)d_in[7];
  const float* Wk  = (const float*)d_in[8];
  const float* bk  = (const float*)d_in[9];
  const float* Wv  = (const float*)d_in[10];
  const float* bv  = (const float*)d_in[11];
  const float* We  = (const float*)d_in[12];
  const float* W1  = (const float*)d_in[13];
  const float* b1  = (const float*)d_in[14];
  const float* W2  = (const float*)d_in[15];
  const float* b2  = (const float*)d_in[16];
  float* out = (float*)d_out;

  // workspace layout:
  // floats: q[5.12M] attn[5.12M] hbuf[10.24M] ssum[160K]
  // ints:   deg[20000] off[20001] cursor[20000] order[320000]  (+pad to 16B)
  // ushort: mbuf[320000*256]
  float* q    = (float*)d_ws;
  float* attn = q + (size_t)N_NODES * 256;
  float* hbuf = attn + (size_t)N_NODES * 256;
  float* ssum = hbuf + (size_t)N_NODES * 512;
  int* deg    = (int*)(ssum + (size_t)N_NODES * 8);
  int* off    = deg + N_NODES;
  int* cursor = off + (N_NODES + 1);
  int* order  = cursor + N_NODES;
  size_t ihead = (size_t)(order + N_EDGES - (int*)d_ws);  // elements of 4B used
  ihead = (ihead + 3) & ~(size_t)3;                       // pad to 16B boundary
  unsigned short* mbuf = (unsigned short*)((int*)d_ws + ihead);

  hipMemsetAsync(ssum, 0, (size_t)N_NODES * 8 * sizeof(float), stream);
  hipMemsetAsync(deg, 0, (size_t)N_NODES * sizeof(int), stream);

  dim3 blk(256);
  // q = x @ Wq + bq
  gemm64<false><<<dim3(4, 313), blk, 0, stream>>>(x, Wq, bq, q, N_NODES, 256, 256);
  // CSR build
  hist_kernel<<<dim3((N_EDGES + 255) / 256), blk, 0, stream>>>(ei, deg);
  scan_kernel<<<dim3(1), dim3(1024), 0, stream>>>(deg, off, cursor);
  scatter_kernel<<<dim3((N_EDGES + 255) / 256), blk, 0, stream>>>(ei, cursor, order);
  // fused edge pass
  edge_fused_kernel<<<dim3(N_EDGES / 32), blk, 0, stream>>>(
      x, p, ea, ei, lnw, lnb, Wk, bk, Wv, bv, We, q, ssum, mbuf);
  // per-node reduction + normalization
  gather_kernel<<<dim3(N_NODES), dim3(64), 0, stream>>>(mbuf, off, order, ssum, attn);
  // MLP
  gemm64<true><<<dim3(8, 313), blk, 0, stream>>>(attn, W1, b1, hbuf, N_NODES, 256, 512);
  gemm64<false><<<dim3(4, 313), blk, 0, stream>>>(hbuf, W2, b2, out, N_NODES, 512, 256);
}

// Round 4
// 1292.057 us; speedup vs baseline: 3.7673x; 2.9699x over previous
//
#include <hip/hip_runtime.h>

#define N_NODES 20000
#define N_EDGES 320000

typedef __attribute__((ext_vector_type(8))) short bf16x8;
typedef __attribute__((ext_vector_type(4))) float f32x4;

__device__ __forceinline__ float4 ld4(const float* p) { return *(const float4*)p; }

__device__ __forceinline__ unsigned short f2bf(float f) {
  unsigned int u = __float_as_uint(f);
  return (unsigned short)((u + 0x7FFFu + ((u >> 16) & 1u)) >> 16);  // RNE
}
__device__ __forceinline__ float bf2f(unsigned short b) {
  return __uint_as_float(((unsigned int)b) << 16);
}
__device__ __forceinline__ float bflo(unsigned int u) { return __uint_as_float(u << 16); }
__device__ __forceinline__ float bfhi(unsigned int u) { return __uint_as_float(u & 0xFFFF0000u); }

// ---------------------------------------------------------------------------
// Generic small GEMM: C[M,N] = act(A[M,K] @ W[K,N] + bias)
// ---------------------------------------------------------------------------
template<bool SILU>
__global__ __launch_bounds__(256) void gemm64(
    const float* __restrict__ A, const float* __restrict__ W,
    const float* __restrict__ bias, float* __restrict__ C,
    int M, int K, int N)
{
  __shared__ __align__(16) float As[32][68];
  __shared__ __align__(16) float Ws[32][68];
  const int m0 = blockIdx.y * 64, n0 = blockIdx.x * 64;
  const int t = threadIdx.x;
  const int tx = t & 15, ty = t >> 4;
  float acc[4][4] = {{0.f,0.f,0.f,0.f},{0.f,0.f,0.f,0.f},{0.f,0.f,0.f,0.f},{0.f,0.f,0.f,0.f}};

  for (int k0 = 0; k0 < K; k0 += 32) {
    {
      const int r = t >> 3, c4 = (t & 7) * 4;
      #pragma unroll
      for (int rr = 0; rr < 64; rr += 32) {
        const int gm = m0 + r + rr;
        float4 v = make_float4(0.f, 0.f, 0.f, 0.f);
        if (gm < M) v = ld4(A + (size_t)gm * K + k0 + c4);
        As[c4 + 0][r + rr] = v.x; As[c4 + 1][r + rr] = v.y;
        As[c4 + 2][r + rr] = v.z; As[c4 + 3][r + rr] = v.w;
      }
      const int wr = t >> 4, wc4 = (t & 15) * 4;
      #pragma unroll
      for (int rr = 0; rr < 32; rr += 16) {
        float4 v = ld4(W + (size_t)(k0 + wr + rr) * N + n0 + wc4);
        *(float4*)&Ws[wr + rr][wc4] = v;
      }
    }
    __syncthreads();
    #pragma unroll
    for (int kk = 0; kk < 32; ++kk) {
      float4 av = *(const float4*)&As[kk][ty * 4];
      float4 bv = *(const float4*)&Ws[kk][tx * 4];
      const float a[4] = {av.x, av.y, av.z, av.w};
      const float b[4] = {bv.x, bv.y, bv.z, bv.w};
      #pragma unroll
      for (int i = 0; i < 4; ++i)
        #pragma unroll
        for (int j = 0; j < 4; ++j)
          acc[i][j] += a[i] * b[j];
    }
    __syncthreads();
  }

  const float4 bv = ld4(bias + n0 + tx * 4);
  const float bb[4] = {bv.x, bv.y, bv.z, bv.w};
  #pragma unroll
  for (int i = 0; i < 4; ++i) {
    const int gm = m0 + ty * 4 + i;
    if (gm < M) {
      float o[4];
      #pragma unroll
      for (int j = 0; j < 4; ++j) {
        float v = acc[i][j] + bb[j];
        if (SILU) v = v / (1.f + __expf(-v));
        o[j] = v;
      }
      float4 ov = make_float4(o[0], o[1], o[2], o[3]);
      *(float4*)&C[(size_t)gm * N + n0 + tx * 4] = ov;
    }
  }
}

// ---------------------------------------------------------------------------
// Weight prep: transpose + bf16 cast. wkT/wvT: [256][576], weT: [256][64].
// ---------------------------------------------------------------------------
__global__ __launch_bounds__(256) void prep_weights(
    const float* __restrict__ Wk, const float* __restrict__ Wv,
    const float* __restrict__ We,
    unsigned short* __restrict__ wkT, unsigned short* __restrict__ wvT,
    unsigned short* __restrict__ weT)
{
  const int id = blockIdx.x * 256 + threadIdx.x;
  if (id < 576 * 256) {
    const int k = id >> 8, c = id & 255;
    wkT[(size_t)c * 576 + k] = f2bf(Wk[id]);
    wvT[(size_t)c * 576 + k] = f2bf(Wv[id]);
  }
  if (id < 64 * 256) {
    const int k = id >> 8, c = id & 255;
    weT[(size_t)c * 64 + k] = f2bf(We[id]);
  }
}

// ---------------------------------------------------------------------------
// MFMA edge pass. Block = 256 thr = 4 waves, 32 edges.
// Wave w owns output cols [w*64, w*64+64) (= heads 2w, 2w+1).
//   featb : LN'd concat features, bf16  [32][584]   (A operand, K=576)
//   eab   : raw edge_attr, bf16         [32][72]    (A operand for eg, K=64)
//   qs    : q[src[e]] rows, fp32        [32][260]
// K/V/eg via v_mfma_f32_16x16x32_bf16; scores in-register from C frags;
// m = exp(score)*v*eg written bf16 (normalization deferred to node pass).
// ---------------------------------------------------------------------------
__global__ __launch_bounds__(256) void edge_mfma_kernel(
    const float* __restrict__ x, const float* __restrict__ p,
    const float* __restrict__ ea, const int* __restrict__ eidx,
    const float* __restrict__ lnw, const float* __restrict__ lnb,
    const unsigned short* __restrict__ wkT, const float* __restrict__ bk,
    const unsigned short* __restrict__ wvT, const float* __restrict__ bv,
    const unsigned short* __restrict__ weT, const float* __restrict__ q,
    float* __restrict__ ssum, unsigned short* __restrict__ mbuf)
{
  __shared__ __align__(16) unsigned short featb[32][584];
  __shared__ __align__(16) float qs[32][260];
  __shared__ __align__(16) unsigned short eab[32][72];
  __shared__ int src_s[32], dst_s[32];

  const int t = threadIdx.x;
  const int eb = blockIdx.x * 32;
  if (t < 32) src_s[t] = eidx[eb + t];
  else if (t < 64) dst_s[t - 32] = eidx[N_EDGES + eb + (t - 32)];
  __syncthreads();

  // ---- gather: feat -> bf16 LDS (+ raw ea copy), q rows -> fp32 LDS ----
  {
    const int cid0 = t >> 4, l16 = t & 15;
    #pragma unroll
    for (int it = 0; it < 18; ++it) {
      const int cid = it * 16 + cid0;  // 0..287
      const int e = cid & 31;
      const int s = cid >> 5;          // 0..8
      const float* sp;
      if (s == 0)      sp = ea + (size_t)(eb + e) * 64 + l16 * 4;
      else if (s <= 4) sp = x + (size_t)src_s[e] * 256 + ((s - 1) * 16 + l16) * 4;
      else             sp = p + (size_t)dst_s[e] * 256 + ((s - 5) * 16 + l16) * 4;
      const float4 v = ld4(sp);
      uint2 pk;
      pk.x = (unsigned int)f2bf(v.x) | ((unsigned int)f2bf(v.y) << 16);
      pk.y = (unsigned int)f2bf(v.z) | ((unsigned int)f2bf(v.w) << 16);
      *(uint2*)&featb[e][(s * 16 + l16) * 4] = pk;
      if (s == 0) *(uint2*)&eab[e][l16 * 4] = pk;
    }
    #pragma unroll
    for (int it = 0; it < 8; ++it) {
      const int idx = it * 256 + t;
      const int e = idx >> 6, c4 = idx & 63;
      const float4 v = ld4(q + (size_t)src_s[e] * 256 + c4 * 4);
      *(float4*)&qs[e][c4 * 4] = v;
    }
  }
  __syncthreads();

  // ---- LayerNorm in place on featb (stats in fp32 from bf16 data) ----
  {
    const int e = t >> 3, g = t & 7;
    float sum = 0.f, sq = 0.f;
    #pragma unroll
    for (int i = 0; i < 9; ++i) {
      const uint4 u = *(const uint4*)&featb[e][(g + 8 * i) * 8];
      const float f0 = bflo(u.x), f1 = bfhi(u.x), f2 = bflo(u.y), f3 = bfhi(u.y);
      const float f4 = bflo(u.z), f5 = bfhi(u.z), f6 = bflo(u.w), f7 = bfhi(u.w);
      sum += (f0 + f1) + (f2 + f3) + (f4 + f5) + (f6 + f7);
      sq += f0*f0 + f1*f1 + f2*f2 + f3*f3 + f4*f4 + f5*f5 + f6*f6 + f7*f7;
    }
    sum += __shfl_xor(sum, 1); sq += __shfl_xor(sq, 1);
    sum += __shfl_xor(sum, 2); sq += __shfl_xor(sq, 2);
    sum += __shfl_xor(sum, 4); sq += __shfl_xor(sq, 4);
    const float mu = sum * (1.f / 576.f);
    const float var = sq * (1.f / 576.f) - mu * mu;
    const float rstd = rsqrtf(var + 1e-5f);
    #pragma unroll
    for (int i = 0; i < 9; ++i) {
      const int ch = g + 8 * i;
      uint4 u = *(const uint4*)&featb[e][ch * 8];
      const float4 w0 = ld4(lnw + ch * 8), w1 = ld4(lnw + ch * 8 + 4);
      const float4 b0 = ld4(lnb + ch * 8), b1 = ld4(lnb + ch * 8 + 4);
      const float o0 = (bflo(u.x) - mu) * rstd * w0.x + b0.x;
      const float o1 = (bfhi(u.x) - mu) * rstd * w0.y + b0.y;
      const float o2 = (bflo(u.y) - mu) * rstd * w0.z + b0.z;
      const float o3 = (bfhi(u.y) - mu) * rstd * w0.w + b0.w;
      const float o4 = (bflo(u.z) - mu) * rstd * w1.x + b1.x;
      const float o5 = (bfhi(u.z) - mu) * rstd * w1.y + b1.y;
      const float o6 = (bflo(u.w) - mu) * rstd * w1.z + b1.z;
      const float o7 = (bfhi(u.w) - mu) * rstd * w1.w + b1.w;
      u.x = (unsigned int)f2bf(o0) | ((unsigned int)f2bf(o1) << 16);
      u.y = (unsigned int)f2bf(o2) | ((unsigned int)f2bf(o3) << 16);
      u.z = (unsigned int)f2bf(o4) | ((unsigned int)f2bf(o5) << 16);
      u.w = (unsigned int)f2bf(o6) | ((unsigned int)f2bf(o7) << 16);
      *(uint4*)&featb[e][ch * 8] = u;
    }
  }
  __syncthreads();

  const int wid = t >> 6, l = t & 63;
  const int lr = l & 15, lg = l >> 4;
  const int j0 = wid * 64;

  // ---- K phase: k = LN(feat) @ Wk + bk ----
  f32x4 kacc[2][4];
  #pragma unroll
  for (int nt = 0; nt < 4; ++nt) {
    const float bb = bk[j0 + nt * 16 + lr];
    f32x4 c; c[0] = bb; c[1] = bb; c[2] = bb; c[3] = bb;
    kacc[0][nt] = c; kacc[1][nt] = c;
  }
  #pragma unroll 2
  for (int ks = 0; ks < 18; ++ks) {
    const bf16x8 a0 = *(const bf16x8*)&featb[lr][ks * 32 + lg * 8];
    const bf16x8 a1 = *(const bf16x8*)&featb[16 + lr][ks * 32 + lg * 8];
    #pragma unroll
    for (int nt = 0; nt < 4; ++nt) {
      const bf16x8 bf = *(const bf16x8*)(wkT + (size_t)(j0 + nt * 16 + lr) * 576 + ks * 32 + lg * 8);
      kacc[0][nt] = __builtin_amdgcn_mfma_f32_16x16x32_bf16(a0, bf, kacc[0][nt], 0, 0, 0);
      kacc[1][nt] = __builtin_amdgcn_mfma_f32_16x16x32_bf16(a1, bf, kacc[1][nt], 0, 0, 0);
    }
  }

  // ---- scores: dot(q[src], k) per (edge, head); butterfly over 16 lanes ----
  float exv[2][4][2];
  #pragma unroll
  for (int mt = 0; mt < 2; ++mt)
    #pragma unroll
    for (int r = 0; r < 4; ++r) {
      const int e = mt * 16 + lg * 4 + r;
      float s0 = kacc[mt][0][r] * qs[e][j0 + lr]      + kacc[mt][1][r] * qs[e][j0 + 16 + lr];
      float s1 = kacc[mt][2][r] * qs[e][j0 + 32 + lr] + kacc[mt][3][r] * qs[e][j0 + 48 + lr];
      s0 += __shfl_xor(s0, 1); s1 += __shfl_xor(s1, 1);
      s0 += __shfl_xor(s0, 2); s1 += __shfl_xor(s1, 2);
      s0 += __shfl_xor(s0, 4); s1 += __shfl_xor(s1, 4);
      s0 += __shfl_xor(s0, 8); s1 += __shfl_xor(s1, 8);
      exv[mt][r][0] = __expf(s0 * 0.17677669529663687f);  // 1/sqrt(32); max-sub skipped
      exv[mt][r][1] = __expf(s1 * 0.17677669529663687f);
    }
  if (lr == 0) {
    #pragma unroll
    for (int mt = 0; mt < 2; ++mt)
      #pragma unroll
      for (int r = 0; r < 4; ++r) {
        const int sn = src_s[mt * 16 + lg * 4 + r];
        atomicAdd(&ssum[(size_t)sn * 8 + wid * 2 + 0], exv[mt][r][0]);
        atomicAdd(&ssum[(size_t)sn * 8 + wid * 2 + 1], exv[mt][r][1]);
      }
  }

  // ---- V phase: v = LN(feat) @ Wv + bv ----
  f32x4 vacc[2][4];
  #pragma unroll
  for (int nt = 0; nt < 4; ++nt) {
    const float bb = bv[j0 + nt * 16 + lr];
    f32x4 c; c[0] = bb; c[1] = bb; c[2] = bb; c[3] = bb;
    vacc[0][nt] = c; vacc[1][nt] = c;
  }
  #pragma unroll 2
  for (int ks = 0; ks < 18; ++ks) {
    const bf16x8 a0 = *(const bf16x8*)&featb[lr][ks * 32 + lg * 8];
    const bf16x8 a1 = *(const bf16x8*)&featb[16 + lr][ks * 32 + lg * 8];
    #pragma unroll
    for (int nt = 0; nt < 4; ++nt) {
      const bf16x8 bf = *(const bf16x8*)(wvT + (size_t)(j0 + nt * 16 + lr) * 576 + ks * 32 + lg * 8);
      vacc[0][nt] = __builtin_amdgcn_mfma_f32_16x16x32_bf16(a0, bf, vacc[0][nt], 0, 0, 0);
      vacc[1][nt] = __builtin_amdgcn_mfma_f32_16x16x32_bf16(a1, bf, vacc[1][nt], 0, 0, 0);
    }
  }

  // ---- eg phase: eg = raw edge_attr @ We (K=64) ----
  f32x4 gacc[2][4];
  #pragma unroll
  for (int nt = 0; nt < 4; ++nt) {
    f32x4 c; c[0] = 0.f; c[1] = 0.f; c[2] = 0.f; c[3] = 0.f;
    gacc[0][nt] = c; gacc[1][nt] = c;
  }
  #pragma unroll
  for (int ks = 0; ks < 2; ++ks) {
    const bf16x8 a0 = *(const bf16x8*)&eab[lr][ks * 32 + lg * 8];
    const bf16x8 a1 = *(const bf16x8*)&eab[16 + lr][ks * 32 + lg * 8];
    #pragma unroll
    for (int nt = 0; nt < 4; ++nt) {
      const bf16x8 bf = *(const bf16x8*)(weT + (size_t)(j0 + nt * 16 + lr) * 64 + ks * 32 + lg * 8);
      gacc[0][nt] = __builtin_amdgcn_mfma_f32_16x16x32_bf16(a0, bf, gacc[0][nt], 0, 0, 0);
      gacc[1][nt] = __builtin_amdgcn_mfma_f32_16x16x32_bf16(a1, bf, gacc[1][nt], 0, 0, 0);
    }
  }

  // ---- m = exv * v * eg -> bf16 scatter (coalesces to 32B per lane-group) ----
  #pragma unroll
  for (int mt = 0; mt < 2; ++mt)
    #pragma unroll
    for (int nt = 0; nt < 4; ++nt)
      #pragma unroll
      for (int r = 0; r < 4; ++r) {
        const int e = eb + mt * 16 + lg * 4 + r;
        const float m = exv[mt][r][nt >> 1] * vacc[mt][nt][r] * gacc[mt][nt][r];
        mbuf[(size_t)e * 256 + j0 + nt * 16 + lr] = f2bf(m);
      }
}

// ---------------------------------------------------------------------------
// CSR build: histogram -> single-block scan -> scatter
// ---------------------------------------------------------------------------
__global__ void hist_kernel(const int* __restrict__ eidx, int* __restrict__ deg)
{
  const int e = blockIdx.x * 256 + threadIdx.x;
  if (e < N_EDGES) atomicAdd(&deg[eidx[e]], 1);
}

__global__ __launch_bounds__(1024) void scan_kernel(
    const int* __restrict__ deg, int* __restrict__ off, int* __restrict__ cursor)
{
  __shared__ int part[1024];
  const int t = threadIdx.x;
  const int base = t * 20;
  int s = 0;
  #pragma unroll 4
  for (int j = 0; j < 20; ++j) {
    const int n = base + j;
    if (n < N_NODES) s += deg[n];
  }
  part[t] = s;
  __syncthreads();
  for (int st = 1; st < 1024; st <<= 1) {
    int v = (t >= st) ? part[t - st] : 0;
    __syncthreads();
    part[t] += v;
    __syncthreads();
  }
  int run = (t == 0) ? 0 : part[t - 1];
  for (int j = 0; j < 20; ++j) {
    const int n = base + j;
    if (n < N_NODES) {
      off[n] = run;
      cursor[n] = run;
      run += deg[n];
    }
  }
  if (t == 1023) off[N_NODES] = part[1023];
}

__global__ void scatter_kernel(const int* __restrict__ eidx,
                               int* __restrict__ cursor, int* __restrict__ order)
{
  const int e = blockIdx.x * 256 + threadIdx.x;
  if (e < N_EDGES) {
    const int s = eidx[e];
    const int pos = atomicAdd(&cursor[s], 1);
    order[pos] = e;
  }
}

// ---------------------------------------------------------------------------
// Node gather: attn[n][c] = (sum_{e in node n} m[e][c]) / ssum[n][c/32]
// ---------------------------------------------------------------------------
__global__ __launch_bounds__(64) void gather_kernel(
    const unsigned short* __restrict__ mbuf, const int* __restrict__ off,
    const int* __restrict__ order, const float* __restrict__ ssum,
    float* __restrict__ attn)
{
  const int n = blockIdx.x;
  const int t = threadIdx.x;
  const int c0 = t * 4;
  const int o0 = off[n], o1 = off[n + 1];
  float a0 = 0.f, a1 = 0.f, a2 = 0.f, a3 = 0.f;
  for (int j = o0; j < o1; ++j) {
    const int e = order[j];
    const ushort4 raw = *(const ushort4*)&mbuf[(size_t)e * 256 + c0];
    a0 += bf2f(raw.x); a1 += bf2f(raw.y); a2 += bf2f(raw.z); a3 += bf2f(raw.w);
  }
  const int h = c0 >> 5;
  float inv = 0.f;
  if (o1 > o0) inv = 1.f / ssum[(size_t)n * 8 + h];
  float4 o = make_float4(a0 * inv, a1 * inv, a2 * inv, a3 * inv);
  *(float4*)&attn[(size_t)n * 256 + c0] = o;
}

// ---------------------------------------------------------------------------
extern "C" void kernel_launch(void* const* d_in, const int* in_sizes, int n_in,
                              void* d_out, int out_size, void* d_ws, size_t ws_size,
                              hipStream_t stream)
{
  const float* x   = (const float*)d_in[0];
  const float* p   = (const float*)d_in[1];
  const float* ea  = (const float*)d_in[2];
  const int*   ei  = (const int*)d_in[3];
  const float* lnw = (const float*)d_in[4];
  const float* lnb = (const float*)d_in[5];
  const float* Wq  = (const float*)d_in[6];
  const float* bq  = (const float*)d_in[7];
  const float* Wk  = (const float*)d_in[8];
  const float* bk  = (const float*)d_in[9];
  const float* Wv  = (const float*)d_in[10];
  const float* bv  = (const float*)d_in[11];
  const float* We  = (const float*)d_in[12];
  const float* W1  = (const float*)d_in[13];
  const float* b1  = (const float*)d_in[14];
  const float* W2  = (const float*)d_in[15];
  const float* b2  = (const float*)d_in[16];
  float* out = (float*)d_out;

  // workspace: q | attn | hbuf | ssum | deg | off | cursor | order | mbuf | wkT | wvT | weT
  float* q    = (float*)d_ws;
  float* attn = q + (size_t)N_NODES * 256;
  float* hbuf = attn + (size_t)N_NODES * 256;
  float* ssum = hbuf + (size_t)N_NODES * 512;
  int* deg    = (int*)(ssum + (size_t)N_NODES * 8);
  int* off    = deg + N_NODES;
  int* cursor = off + (N_NODES + 1);
  int* order  = cursor + N_NODES;
  size_t ihead = (size_t)(order + N_EDGES - (int*)d_ws);
  ihead = (ihead + 3) & ~(size_t)3;  // 16B align
  unsigned short* mbuf = (unsigned short*)((int*)d_ws + ihead);
  unsigned short* wkT = mbuf + (size_t)N_EDGES * 256;   // 163.84MB offset, 16B-aligned
  unsigned short* wvT = wkT + (size_t)256 * 576;
  unsigned short* weT = wvT + (size_t)256 * 576;

  hipMemsetAsync(ssum, 0, (size_t)N_NODES * 8 * sizeof(float), stream);
  hipMemsetAsync(deg, 0, (size_t)N_NODES * sizeof(int), stream);

  dim3 blk(256);
  prep_weights<<<dim3(576), blk, 0, stream>>>(Wk, Wv, We, wkT, wvT, weT);
  // q = x @ Wq + bq
  gemm64<false><<<dim3(4, 313), blk, 0, stream>>>(x, Wq, bq, q, N_NODES, 256, 256);
  // CSR build
  hist_kernel<<<dim3((N_EDGES + 255) / 256), blk, 0, stream>>>(ei, deg);
  scan_kernel<<<dim3(1), dim3(1024), 0, stream>>>(deg, off, cursor);
  scatter_kernel<<<dim3((N_EDGES + 255) / 256), blk, 0, stream>>>(ei, cursor, order);
  // fused MFMA edge pass
  edge_mfma_kernel<<<dim3(N_EDGES / 32), blk, 0, stream>>>(
      x, p, ea, ei, lnw, lnb, wkT, bk, wvT, bv, weT, q, ssum, mbuf);
  // per-node reduction + normalization
  gather_kernel<<<dim3(N_NODES), dim3(64), 0, stream>>>(mbuf, off, order, ssum, attn);
  // MLP
  gemm64<true><<<dim3(8, 313), blk, 0, stream>>>(attn, W1, b1, hbuf, N_NODES, 256, 512);
  gemm64<false><<<dim3(4, 313), blk, 0, stream>>>(hbuf, W2, b2, out, N_NODES, 512, 256);
}